// Round 7
// baseline (327.211 us; speedup 1.0000x reference)
//
#include <hip/hip_runtime.h>
#include <hip/hip_bf16.h>

typedef unsigned short u16;
typedef __bf16 bf16x8 __attribute__((ext_vector_type(8)));
typedef float f32x4 __attribute__((ext_vector_type(4)));

#define N_ROWS 8192
#define M_ROWS 4096
#define E_DIM  512
#define KSPLIT 4
#define INV_T  0.04419417382415922f   // 1/22.627416997969522

// ---------- helpers ----------
__device__ __forceinline__ u16 f2bf(float f) {
    unsigned u = __float_as_uint(f);
    u += 0x7FFF + ((u >> 16) & 1);   // RNE
    return (u16)(u >> 16);
}
__device__ __forceinline__ float bf2f(u16 u) {
    return __uint_as_float(((unsigned)u) << 16);
}

#define GLD16(gp, lp) \
    __builtin_amdgcn_global_load_lds((const __attribute__((address_space(1))) void*)(gp), \
                                     (__attribute__((address_space(3))) void*)(lp), 16, 0, 0)

// ---------- cast fp32 -> bf16, 4 elems/thread ----------
__global__ __launch_bounds__(256)
void cast_bf(const float* __restrict__ in, u16* __restrict__ out, int n4) {
    int i = blockIdx.x * 256 + threadIdx.x;
    if (i < n4) {
        float4 f = reinterpret_cast<const float4*>(in)[i];
        ushort4 o;
        o.x = f2bf(f.x); o.y = f2bf(f.y); o.z = f2bf(f.z); o.w = f2bf(f.w);
        reinterpret_cast<ushort4*>(out)[i] = o;
    }
}

// ---------- bf16 tiled transpose: out[c][r] = in[r][c]; R,C multiples of 64 ----------
__global__ __launch_bounds__(256)
void transpose_bf(const u16* __restrict__ in, u16* __restrict__ out, int R, int C) {
    __shared__ u16 t[64][72];
    const int r0 = blockIdx.y * 64, c0 = blockIdx.x * 64;
    const int tid = threadIdx.x;
    const int lr = tid >> 2, lc = (tid & 3) * 16;
    const u16* src = in + (size_t)(r0 + lr) * C + c0 + lc;
    *reinterpret_cast<uint4*>(&t[lr][lc])     = *reinterpret_cast<const uint4*>(src);
    *reinterpret_cast<uint4*>(&t[lr][lc + 8]) = *reinterpret_cast<const uint4*>(src + 8);
    __syncthreads();
    u16 tmp[16];
#pragma unroll
    for (int j = 0; j < 16; ++j) tmp[j] = t[lc + j][lr];
    u16* dst = out + (size_t)(c0 + lr) * R + r0 + lc;
    *reinterpret_cast<uint4*>(dst)     = *reinterpret_cast<uint4*>(&tmp[0]);
    *reinterpret_cast<uint4*>(dst + 8) = *reinterpret_cast<uint4*>(&tmp[8]);
}

// ---------- 128x256 MFMA GEMM body (projections / wqkT) ----------
// C[i][j] = sum_k A[i][k]*B[j][k]; A,B bf16 K-contiguous.
// mode: 0 = fp32 row-major, 1 = bf16 row-major
__device__ __forceinline__
void gemm_wide_body(const u16* __restrict__ A, int lda,
                    const u16* __restrict__ B, int ldb,
                    void* __restrict__ C, int ldc, int K,
                    int row0, int col0, int mode) {
    __shared__ u16 sA[2][128 * 32];
    __shared__ u16 sB[2][256 * 32];

    const int tid  = threadIdx.x;
    const int wave = tid >> 6, lane = tid & 63;
    const int quad = lane >> 4, m16 = lane & 15;
    const int wr = (wave & 1) * 64;
    const int wc = (wave >> 1) * 128;

    const int srow  = lane >> 2;
    const int skoff = (lane & 3) * 8;
    const u16* ag0 = A + (size_t)(row0 + wave * 16 + srow) * lda + skoff;
    const u16* ag1 = ag0 + (size_t)64 * lda;
    const u16* bg0 = B + (size_t)(col0 + wave * 16 + srow) * ldb + skoff;
    const u16* bg1 = bg0 + (size_t)64 * ldb;
    const u16* bg2 = bg0 + (size_t)128 * ldb;
    const u16* bg3 = bg0 + (size_t)192 * ldb;
    const int loa0 = (wave * 16) * 32;
    const int loa1 = (wave * 16 + 64) * 32;
    const int lob0 = (wave * 16) * 32;
    const int lob1 = (wave * 16 + 64) * 32;
    const int lob2 = (wave * 16 + 128) * 32;
    const int lob3 = (wave * 16 + 192) * 32;

    f32x4 acc[4][8];
#pragma unroll
    for (int i = 0; i < 4; ++i)
#pragma unroll
        for (int j = 0; j < 8; ++j) acc[i][j] = (f32x4){0.f, 0.f, 0.f, 0.f};

    GLD16(ag0, &sA[0][loa0]); GLD16(ag1, &sA[0][loa1]);
    GLD16(bg0, &sB[0][lob0]); GLD16(bg1, &sB[0][lob1]);
    GLD16(bg2, &sB[0][lob2]); GLD16(bg3, &sB[0][lob3]);

    int kb = 0;
    for (int k0 = 0; k0 < K; k0 += 32, kb ^= 1) {
        __syncthreads();
        const int kn = (k0 + 32 < K) ? (k0 + 32) : 0;
        GLD16(ag0 + kn, &sA[kb ^ 1][loa0]); GLD16(ag1 + kn, &sA[kb ^ 1][loa1]);
        GLD16(bg0 + kn, &sB[kb ^ 1][lob0]); GLD16(bg1 + kn, &sB[kb ^ 1][lob1]);
        GLD16(bg2 + kn, &sB[kb ^ 1][lob2]); GLD16(bg3 + kn, &sB[kb ^ 1][lob3]);

        bf16x8 a[4], b[8];
#pragma unroll
        for (int i = 0; i < 4; ++i)
            a[i] = *reinterpret_cast<const bf16x8*>(&sA[kb][(wr + i * 16 + m16) * 32 + quad * 8]);
#pragma unroll
        for (int j = 0; j < 8; ++j)
            b[j] = *reinterpret_cast<const bf16x8*>(&sB[kb][(wc + j * 16 + m16) * 32 + quad * 8]);
#pragma unroll
        for (int i = 0; i < 4; ++i)
#pragma unroll
            for (int j = 0; j < 8; ++j)
                acc[i][j] = __builtin_amdgcn_mfma_f32_16x16x32_bf16(a[i], b[j], acc[i][j], 0, 0, 0);
    }

#pragma unroll
    for (int i = 0; i < 4; ++i) {
        const int rbase = row0 + wr + i * 16 + quad * 4;
#pragma unroll
        for (int j = 0; j < 8; ++j) {
            const int c = col0 + wc + j * 16 + m16;
#pragma unroll
            for (int r = 0; r < 4; ++r) {
                const float v = acc[i][j][r];
                const int rr = rbase + r;
                if (mode == 0) {
                    reinterpret_cast<float*>(C)[(size_t)rr * ldc + c] = v;
                } else {
                    reinterpret_cast<u16*>(C)[(size_t)rr * ldc + c] = f2bf(v);
                }
            }
        }
    }
}

// ---------- batched projection GEMMs ----------
struct ProjArgs {
    const u16* A[3];
    const u16* B[3];
    void*      C[3];
    int        rows[3];
    int        mode[3];
    int        ldc[3];
};

__global__ __launch_bounds__(256, 2)
void proj_gemm(ProjArgs p) {
    const int z = blockIdx.z;
    const int row0 = blockIdx.y * 128;
    if (row0 >= p.rows[z]) return;
    gemm_wide_body(p.A[z], E_DIM, p.B[z], E_DIM, p.C[z], p.ldc[z], E_DIM,
                   row0, blockIdx.x * 256, p.mode[z]);
}

__global__ __launch_bounds__(256, 2)
void gemm_main(const u16* __restrict__ A, int lda,
               const u16* __restrict__ B, int ldb,
               void* __restrict__ C, int ldc, int K, int mode) {
    gemm_wide_body(A, lda, B, ldb, C, ldc, K,
                   blockIdx.y * 128, blockIdx.x * 256, mode);
}

// ---------- fused flash score+exp+PV ----------
// Per block: Q-tile 64 rows (q0), j-slice 1024 (zj). 512 threads = 8 waves.
// chunk loop (4x256 j): S = T*obs^T (K=512, dbuf), exp -> sP (LDS), O += P*V.
// sOV is phase-shared: obs dbuf in S phase, flat 512x32 V buffer in PV phase.
__global__ __launch_bounds__(512, 1)
void flash_pv(const u16* __restrict__ T, const u16* __restrict__ OBS,
              const u16* __restrict__ VT, u16* __restrict__ O,
              float* __restrict__ psum) {
    __shared__ u16 sT[2][64 * 32];     // 8 KB
    __shared__ u16 sOV[2][256 * 32];   // 32 KB (union: obs dbuf / V flat)
    __shared__ u16 sP[64 * 264];       // 33 KB, stride 264 (16B-aligned rows, conflict break)

    const int b = blockIdx.x;
    const int zj = (b & 7) >> 1;                    // XCD-stable j-slice
    const int q0 = ((b >> 3) * 2 + (b & 1)) * 64;
    const int tid = threadIdx.x;
    const int wave = tid >> 6, lane = tid & 63;
    const int quad = lane >> 4, m16 = lane & 15;
    const int srow = lane >> 2, skoff = (lane & 3) * 8;
    const int tl = wave * 512 + lane * 8;           // wave-uniform base + lane*16B

    const u16* tg  = T + (size_t)(q0 + wave * 16 + srow) * E_DIM + skoff;  // used by waves 0-3
    const u16* vt0 = VT + (size_t)(wave * 16 + srow) * M_ROWS + skoff;

    f32x4 accO[4][4];
#pragma unroll
    for (int i = 0; i < 4; ++i)
#pragma unroll
        for (int j = 0; j < 4; ++j) accO[i][j] = (f32x4){0.f, 0.f, 0.f, 0.f};
    float racc[4][4];
#pragma unroll
    for (int i = 0; i < 4; ++i)
#pragma unroll
        for (int r = 0; r < 4; ++r) racc[i][r] = 0.f;

    for (int c = 0; c < 4; ++c) {
        const int jb = zj * 1024 + c * 256;
        const u16* og = OBS + (size_t)(jb + wave * 16 + srow) * E_DIM + skoff;

        f32x4 accS[4][2];
#pragma unroll
        for (int i = 0; i < 4; ++i) {
            accS[i][0] = (f32x4){0.f, 0.f, 0.f, 0.f};
            accS[i][1] = (f32x4){0.f, 0.f, 0.f, 0.f};
        }

        __syncthreads();   // all reads of sT/sOV/sP from previous chunk complete
        if (wave < 4) GLD16(tg, &sT[0][tl]);
        GLD16(og,               &sOV[0][tl]);
        GLD16(og + 128 * E_DIM, &sOV[0][tl + 4096]);

        int kb = 0;
        for (int k0 = 0; k0 < E_DIM; k0 += 32, kb ^= 1) {
            __syncthreads();   // buf[kb] landed; prior reads of buf[kb^1] done
            if (k0 + 32 < E_DIM) {
                if (wave < 4) GLD16(tg + k0 + 32, &sT[kb ^ 1][tl]);
                GLD16(og + k0 + 32,               &sOV[kb ^ 1][tl]);
                GLD16(og + 128 * E_DIM + k0 + 32, &sOV[kb ^ 1][tl + 4096]);
            }
            bf16x8 a[4], bb[2];
#pragma unroll
            for (int i = 0; i < 4; ++i)
                a[i] = *reinterpret_cast<const bf16x8*>(&sT[kb][(i * 16 + m16) * 32 + quad * 8]);
#pragma unroll
            for (int j = 0; j < 2; ++j)
                bb[j] = *reinterpret_cast<const bf16x8*>(
                    &sOV[kb][(wave * 32 + j * 16 + m16) * 32 + quad * 8]);
#pragma unroll
            for (int i = 0; i < 4; ++i)
#pragma unroll
                for (int j = 0; j < 2; ++j)
                    accS[i][j] = __builtin_amdgcn_mfma_f32_16x16x32_bf16(a[i], bb[j], accS[i][j], 0, 0, 0);
        }

        // exp -> sP (C-layout scatter) + per-row partial sums (no max subtraction: fp32-safe)
#pragma unroll
        for (int i = 0; i < 4; ++i) {
            float rs[4] = {0.f, 0.f, 0.f, 0.f};
#pragma unroll
            for (int j = 0; j < 2; ++j) {
                const int col = wave * 32 + j * 16 + m16;
#pragma unroll
                for (int r = 0; r < 4; ++r) {
                    const float v = __expf(accS[i][j][r] * INV_T);
                    rs[r] += v;
                    sP[(i * 16 + quad * 4 + r) * 264 + col] = f2bf(v);
                }
            }
#pragma unroll
            for (int r = 0; r < 4; ++r) {
                float s = rs[r];
                s += __shfl_down(s, 8, 16);
                s += __shfl_down(s, 4, 16);
                s += __shfl_down(s, 2, 16);
                s += __shfl_down(s, 1, 16);
                racc[i][r] += s;   // meaningful on m16==0 lanes
            }
        }

        // PV: O(64x512) += P(64x256) @ V(256 x 512), V rows = e from obsvT
        u16* sV = &sOV[0][0];   // 512x32 flat
        for (int jj = 0; jj < 256; jj += 32) {
            __syncthreads();   // prior jj reads done; (jj==0) sP writes + last k-iter reads drained
            const u16* v0 = vt0 + jb + jj;
            GLD16(v0,                &sV[tl]);
            GLD16(v0 + 128 * M_ROWS, &sV[tl + 4096]);
            GLD16(v0 + 256 * M_ROWS, &sV[tl + 8192]);
            GLD16(v0 + 384 * M_ROWS, &sV[tl + 12288]);
            __syncthreads();   // V landed
            bf16x8 a2[4], b2[4];
#pragma unroll
            for (int i = 0; i < 4; ++i)
                a2[i] = *reinterpret_cast<const bf16x8*>(&sP[(i * 16 + m16) * 264 + jj + quad * 8]);
#pragma unroll
            for (int j = 0; j < 4; ++j)
                b2[j] = *reinterpret_cast<const bf16x8*>(
                    &sV[(wave * 64 + j * 16 + m16) * 32 + quad * 8]);
#pragma unroll
            for (int i = 0; i < 4; ++i)
#pragma unroll
                for (int j = 0; j < 4; ++j)
                    accO[i][j] = __builtin_amdgcn_mfma_f32_16x16x32_bf16(a2[i], b2[j], accO[i][j], 0, 0, 0);
        }
    }

    // epilogue: O slice zj (bf16), psum partials
    u16* Oz = O + (size_t)zj * N_ROWS * E_DIM;
#pragma unroll
    for (int i = 0; i < 4; ++i) {
        const int rbase = q0 + i * 16 + quad * 4;
#pragma unroll
        for (int j = 0; j < 4; ++j) {
            const int cc = wave * 64 + j * 16 + m16;
#pragma unroll
            for (int r = 0; r < 4; ++r)
                Oz[(size_t)(rbase + r) * E_DIM + cc] = f2bf(accO[i][j][r]);
        }
    }
    if (m16 == 0) {
        float* ps = psum + (size_t)(zj * 8 + wave) * N_ROWS;
#pragma unroll
        for (int i = 0; i < 4; ++i)
#pragma unroll
            for (int r = 0; r < 4; ++r)
                ps[q0 + i * 16 + quad * 4 + r] = racc[i][r];
    }
}

// ---------- self attention score: dot(T[n], vcode[n]) ----------
__global__ __launch_bounds__(256)
void self_dot(const u16* __restrict__ q, const u16* __restrict__ k,
              float* __restrict__ selfS) {
    const int wave = threadIdx.x >> 6, lane = threadIdx.x & 63;
    const int row = blockIdx.x * 4 + wave;
    const uint4 qa = *reinterpret_cast<const uint4*>(q + (size_t)row * E_DIM + lane * 8);
    const uint4 ka = *reinterpret_cast<const uint4*>(k + (size_t)row * E_DIM + lane * 8);
    unsigned qu[4] = {qa.x, qa.y, qa.z, qa.w};
    unsigned ku[4] = {ka.x, ka.y, ka.z, ka.w};
    float s = 0.f;
#pragma unroll
    for (int i = 0; i < 4; ++i) {
        s += bf2f((u16)(qu[i] & 0xFFFF)) * bf2f((u16)(ku[i] & 0xFFFF));
        s += bf2f((u16)(qu[i] >> 16))    * bf2f((u16)(ku[i] >> 16));
    }
#pragma unroll
    for (int off = 32; off; off >>= 1) s += __shfl_down(s, off);
    if (lane == 0) selfS[row] = s;
}

// ---------- combine 32 partial row sums -> inv_l, p0 ----------
__global__ __launch_bounds__(256)
void sum_combine(const float* __restrict__ psum, const float* __restrict__ selfS,
                 float* __restrict__ p0_out, float* __restrict__ invl_out) {
    const int n = blockIdx.x * 256 + threadIdx.x;
    float l = 0.f;
#pragma unroll
    for (int j = 0; j < 32; ++j) l += psum[(size_t)j * N_ROWS + n];
    const float p0 = expf(selfS[n] * INV_T);
    l += p0;
    p0_out[n] = p0;
    invl_out[n] = 1.f / l;
}

// ---------- epilogue: LN(inv_l*(p0*v_value + sum_z O_z) + v_code) ----------
__global__ __launch_bounds__(256)
void final_ln(const u16* __restrict__ O, const u16* __restrict__ vval,
              const float* __restrict__ p0v, const float* __restrict__ invl,
              const float* __restrict__ vcode,
              const float* __restrict__ gamma, const float* __restrict__ beta,
              float* __restrict__ out) {
    __shared__ float lds[8];
    const int n = blockIdx.x, t = threadIdx.x;
    const int lane = t & 63, wave = t >> 6;
    const size_t base = (size_t)n * E_DIM;
    const size_t NE = (size_t)N_ROWS * E_DIM;
    const float a = p0v[n], il = invl[n];

    float o0 = 0.f, o1 = 0.f;
#pragma unroll
    for (int z = 0; z < KSPLIT; ++z) {
        o0 += bf2f(O[z * NE + base + t]);
        o1 += bf2f(O[z * NE + base + t + 256]);
    }
    float x0 = fmaf(a, bf2f(vval[base + t]),       o0) * il + vcode[base + t];
    float x1 = fmaf(a, bf2f(vval[base + t + 256]), o1) * il + vcode[base + t + 256];

    float s = x0 + x1;
#pragma unroll
    for (int off = 32; off; off >>= 1) s += __shfl_down(s, off);
    if (lane == 0) lds[wave] = s;
    __syncthreads();
    const float mu = (lds[0] + lds[1] + lds[2] + lds[3]) * (1.0f / E_DIM);
    __syncthreads();

    const float d0 = x0 - mu, d1 = x1 - mu;
    float vs = d0 * d0 + d1 * d1;
#pragma unroll
    for (int off = 32; off; off >>= 1) vs += __shfl_down(vs, off);
    if (lane == 0) lds[wave] = vs;
    __syncthreads();
    const float var = (lds[0] + lds[1] + lds[2] + lds[3]) * (1.0f / E_DIM);
    const float rs = rsqrtf(var + 1e-6f);

    out[base + t]       = d0 * rs * gamma[t]       + beta[t];
    out[base + t + 256] = d1 * rs * gamma[t + 256] + beta[t + 256];
}

// ---------- workspace layout (bytes; total ~72 MiB) ----------
#define OFF_VCODEBF 0ull
#define OFF_OBSBF   8388608ull
#define OFF_WQ      12582912ull
#define OFF_WK      13107200ull
#define OFF_WV      13631488ull
#define OFF_WQT     14155776ull
#define OFF_WKT     14680064ull
#define OFF_WQKT    15204352ull
#define OFF_TBF     15728640ull
#define OFF_OBSV    24117248ull
#define OFF_OBSVT   28311552ull
#define OFF_VVAL    32505856ull
#define OFF_O       40894464ull      // KSPLIT bf16 slices (32 MiB)
#define OFF_P0      74448896ull
#define OFF_SELF    74481664ull
#define OFF_INVL    74514432ull
#define OFF_PSUM    74547200ull      // 32 x 8192 fp32 = 1 MiB

extern "C" void kernel_launch(void* const* d_in, const int* in_sizes, int n_in,
                              void* d_out, int out_size, void* d_ws, size_t ws_size,
                              hipStream_t stream) {
    const float* v_code   = (const float*)d_in[0];
    const float* obs_code = (const float*)d_in[1];
    const float* Wq       = (const float*)d_in[2];
    const float* Wk       = (const float*)d_in[3];
    const float* Wv       = (const float*)d_in[4];
    const float* gamma    = (const float*)d_in[5];
    const float* beta     = (const float*)d_in[6];
    float* out = (float*)d_out;
    char* ws = (char*)d_ws;

    u16* vcode_bf = (u16*)(ws + OFF_VCODEBF);
    u16* obs_bf   = (u16*)(ws + OFF_OBSBF);
    u16* wq_bf    = (u16*)(ws + OFF_WQ);
    u16* wk_bf    = (u16*)(ws + OFF_WK);
    u16* wv_bf    = (u16*)(ws + OFF_WV);
    u16* wqT      = (u16*)(ws + OFF_WQT);
    u16* wkT      = (u16*)(ws + OFF_WKT);
    u16* wqkT     = (u16*)(ws + OFF_WQKT);
    u16* t_bf     = (u16*)(ws + OFF_TBF);
    u16* obsv_bf  = (u16*)(ws + OFF_OBSV);
    u16* obsvT_bf = (u16*)(ws + OFF_OBSVT);
    u16* vval     = (u16*)(ws + OFF_VVAL);
    u16* O        = (u16*)(ws + OFF_O);
    float* p0v    = (float*)(ws + OFF_P0);
    float* selfS  = (float*)(ws + OFF_SELF);
    float* invl   = (float*)(ws + OFF_INVL);
    float* psum   = (float*)(ws + OFF_PSUM);

    // 1. casts
    cast_bf<<<N_ROWS * E_DIM / 4 / 256, 256, 0, stream>>>(v_code, vcode_bf, N_ROWS * E_DIM / 4);
    cast_bf<<<M_ROWS * E_DIM / 4 / 256, 256, 0, stream>>>(obs_code, obs_bf, M_ROWS * E_DIM / 4);
    cast_bf<<<E_DIM * E_DIM / 4 / 256, 256, 0, stream>>>(Wq, wq_bf, E_DIM * E_DIM / 4);
    cast_bf<<<E_DIM * E_DIM / 4 / 256, 256, 0, stream>>>(Wk, wk_bf, E_DIM * E_DIM / 4);
    cast_bf<<<E_DIM * E_DIM / 4 / 256, 256, 0, stream>>>(Wv, wv_bf, E_DIM * E_DIM / 4);

    // 2. transpose Wq, Wk
    transpose_bf<<<dim3(8, 8), 256, 0, stream>>>(wq_bf, wqT, E_DIM, E_DIM);
    transpose_bf<<<dim3(8, 8), 256, 0, stream>>>(wk_bf, wkT, E_DIM, E_DIM);

    // 3. WqkT = (Wq^T Wk)^T
    gemm_main<<<dim3(E_DIM / 256, E_DIM / 128, 1), 256, 0, stream>>>(
        wkT, E_DIM, wqT, E_DIM, wqkT, E_DIM, E_DIM, 1);

    // 4. projections: vval (bf16), obsv (bf16), T = vcode@Wqk (bf16)
    ProjArgs p;
    p.A[0] = vcode_bf; p.B[0] = wv_bf; p.C[0] = vval;    p.rows[0] = N_ROWS; p.mode[0] = 1; p.ldc[0] = E_DIM;
    p.A[1] = obs_bf;   p.B[1] = wv_bf; p.C[1] = obsv_bf; p.rows[1] = M_ROWS; p.mode[1] = 1; p.ldc[1] = E_DIM;
    p.A[2] = vcode_bf; p.B[2] = wqkT;  p.C[2] = t_bf;    p.rows[2] = N_ROWS; p.mode[2] = 1; p.ldc[2] = E_DIM;
    proj_gemm<<<dim3(E_DIM / 256, N_ROWS / 128, 3), 256, 0, stream>>>(p);

    // 5. transpose obsv -> obsvT [512 x 4096]
    transpose_bf<<<dim3(E_DIM / 64, M_ROWS / 64), 256, 0, stream>>>(obsv_bf, obsvT_bf, M_ROWS, E_DIM);

    // 6. self score
    self_dot<<<N_ROWS / 4, 256, 0, stream>>>(t_bf, vcode_bf, selfS);

    // 7. fused score+exp+PV: O_z slices + psum partials (512 blocks, XCD-swizzled)
    flash_pv<<<512, 512, 0, stream>>>(t_bf, obs_bf, obsvT_bf, O, psum);

    // 8. combine partials + self term
    sum_combine<<<N_ROWS / 256, 256, 0, stream>>>(psum, selfS, p0v, invl);

    // 9. residual + LayerNorm
    final_ln<<<N_ROWS, 256, 0, stream>>>(O, vval, p0v, invl, v_code, gamma, beta, out);
}

// Round 8
// 255.750 us; speedup vs baseline: 1.2794x; 1.2794x over previous
//
#include <hip/hip_runtime.h>
#include <hip/hip_bf16.h>

typedef unsigned short u16;
typedef unsigned char u8;
typedef __bf16 bf16x8 __attribute__((ext_vector_type(8)));
typedef float f32x4 __attribute__((ext_vector_type(4)));

#define N_ROWS 8192
#define M_ROWS 4096
#define E_DIM  512
#define KSPLIT 4
#define INV_T  0.04419417382415922f   // 1/22.627416997969522

// ---------- helpers ----------
__device__ __forceinline__ u16 f2bf(float f) {
    unsigned u = __float_as_uint(f);
    u += 0x7FFF + ((u >> 16) & 1);   // RNE
    return (u16)(u >> 16);
}
__device__ __forceinline__ float bf2f(u16 u) {
    return __uint_as_float(((unsigned)u) << 16);
}
__device__ __forceinline__ u8 f2fp8(float f) {
    // OCP e4m3fn via HW packed convert (gfx950)
    int p = __builtin_amdgcn_cvt_pk_fp8_f32(f, f, 0, false);
    return (u8)(p & 0xFF);
}

#define GLD16(gp, lp) \
    __builtin_amdgcn_global_load_lds((const __attribute__((address_space(1))) void*)(gp), \
                                     (__attribute__((address_space(3))) void*)(lp), 16, 0, 0)

// ---------- cast fp32 -> bf16, 4 elems/thread ----------
__global__ __launch_bounds__(256)
void cast_bf(const float* __restrict__ in, u16* __restrict__ out, int n4) {
    int i = blockIdx.x * 256 + threadIdx.x;
    if (i < n4) {
        float4 f = reinterpret_cast<const float4*>(in)[i];
        ushort4 o;
        o.x = f2bf(f.x); o.y = f2bf(f.y); o.z = f2bf(f.z); o.w = f2bf(f.w);
        reinterpret_cast<ushort4*>(out)[i] = o;
    }
}

// ---------- 3 weight casts in one launch ----------
struct WCastArgs { const float* src[3]; u16* dst[3]; };
__global__ __launch_bounds__(256)
void cast_w3(WCastArgs a) {
    const int z = blockIdx.z;
    const int i = blockIdx.x * 256 + threadIdx.x;   // n4 = 65536
    float4 f = reinterpret_cast<const float4*>(a.src[z])[i];
    ushort4 o;
    o.x = f2bf(f.x); o.y = f2bf(f.y); o.z = f2bf(f.z); o.w = f2bf(f.w);
    reinterpret_cast<ushort4*>(a.dst[z])[i] = o;
}

// ---------- bf16 tiled transpose, two tensors per launch (z) ----------
__global__ __launch_bounds__(256)
void transpose_w2(const u16* __restrict__ in0, u16* __restrict__ out0,
                  const u16* __restrict__ in1, u16* __restrict__ out1) {
    __shared__ u16 t[64][72];
    const u16* in = blockIdx.z ? in1 : in0;
    u16* out      = blockIdx.z ? out1 : out0;
    const int R = E_DIM, C = E_DIM;
    const int r0 = blockIdx.y * 64, c0 = blockIdx.x * 64;
    const int tid = threadIdx.x;
    const int lr = tid >> 2, lc = (tid & 3) * 16;
    const u16* src = in + (size_t)(r0 + lr) * C + c0 + lc;
    *reinterpret_cast<uint4*>(&t[lr][lc])     = *reinterpret_cast<const uint4*>(src);
    *reinterpret_cast<uint4*>(&t[lr][lc + 8]) = *reinterpret_cast<const uint4*>(src + 8);
    __syncthreads();
    u16 tmp[16];
#pragma unroll
    for (int j = 0; j < 16; ++j) tmp[j] = t[lc + j][lr];
    u16* dst = out + (size_t)(c0 + lr) * R + r0 + lc;
    *reinterpret_cast<uint4*>(dst)     = *reinterpret_cast<uint4*>(&tmp[0]);
    *reinterpret_cast<uint4*>(dst + 8) = *reinterpret_cast<uint4*>(&tmp[8]);
}

// ---------- bf16 [R x C] -> fp8 transposed [C x R] ----------
__global__ __launch_bounds__(256)
void transpose_to_fp8(const u16* __restrict__ in, u8* __restrict__ out, int R, int C) {
    __shared__ u16 t[64][72];
    const int r0 = blockIdx.y * 64, c0 = blockIdx.x * 64;
    const int tid = threadIdx.x;
    const int lr = tid >> 2, lc = (tid & 3) * 16;
    const u16* src = in + (size_t)(r0 + lr) * C + c0 + lc;
    *reinterpret_cast<uint4*>(&t[lr][lc])     = *reinterpret_cast<const uint4*>(src);
    *reinterpret_cast<uint4*>(&t[lr][lc + 8]) = *reinterpret_cast<const uint4*>(src + 8);
    __syncthreads();
    unsigned w[4];
#pragma unroll
    for (int g = 0; g < 4; ++g) {
        float f0 = bf2f(t[lc + 4 * g + 0][lr]);
        float f1 = bf2f(t[lc + 4 * g + 1][lr]);
        float f2 = bf2f(t[lc + 4 * g + 2][lr]);
        float f3 = bf2f(t[lc + 4 * g + 3][lr]);
        int p01 = __builtin_amdgcn_cvt_pk_fp8_f32(f0, f1, 0, false);
        int p23 = __builtin_amdgcn_cvt_pk_fp8_f32(f2, f3, 0, false);
        w[g] = (unsigned)(p01 & 0xFFFF) | ((unsigned)p23 << 16);
    }
    u8* dst = out + (size_t)(c0 + lr) * R + r0 + lc;
    *reinterpret_cast<uint4*>(dst) = (uint4){w[0], w[1], w[2], w[3]};
}

// ---------- 128x256 MFMA GEMM body (bf16 in), single-barrier dbuf pipeline ----------
// C[i][j] = sum_k A[i][k]*B[j][k]; A,B bf16 K-contiguous.
// mode: 1 = bf16 row-major out; 2 = fp8 exp(acc*INV_T) out + per-row partial sums
__device__ __forceinline__
void gemm_wide_body(const u16* __restrict__ A, int lda,
                    const u16* __restrict__ B, int ldb,
                    void* __restrict__ C, int ldc, int K,
                    int row0, int col0, int mode, float* __restrict__ psum) {
    __shared__ u16 sA[2][128 * 32];
    __shared__ u16 sB[2][256 * 32];

    const int tid  = threadIdx.x;
    const int wave = tid >> 6, lane = tid & 63;
    const int quad = lane >> 4, m16 = lane & 15;
    const int wr = (wave & 1) * 64;
    const int wc = (wave >> 1) * 128;

    const int srow  = lane >> 2;
    const int skoff = (lane & 3) * 8;
    const u16* ag0 = A + (size_t)(row0 + wave * 16 + srow) * lda + skoff;
    const u16* ag1 = ag0 + (size_t)64 * lda;
    const u16* bg0 = B + (size_t)(col0 + wave * 16 + srow) * ldb + skoff;
    const u16* bg1 = bg0 + (size_t)64 * ldb;
    const u16* bg2 = bg0 + (size_t)128 * ldb;
    const u16* bg3 = bg0 + (size_t)192 * ldb;
    const int loa0 = (wave * 16) * 32;
    const int loa1 = (wave * 16 + 64) * 32;
    const int lob0 = (wave * 16) * 32;
    const int lob1 = (wave * 16 + 64) * 32;
    const int lob2 = (wave * 16 + 128) * 32;
    const int lob3 = (wave * 16 + 192) * 32;

    f32x4 acc[4][8];
#pragma unroll
    for (int i = 0; i < 4; ++i)
#pragma unroll
        for (int j = 0; j < 8; ++j) acc[i][j] = (f32x4){0.f, 0.f, 0.f, 0.f};

    GLD16(ag0, &sA[0][loa0]); GLD16(ag1, &sA[0][loa1]);
    GLD16(bg0, &sB[0][lob0]); GLD16(bg1, &sB[0][lob1]);
    GLD16(bg2, &sB[0][lob2]); GLD16(bg3, &sB[0][lob3]);

    int kb = 0;
    for (int k0 = 0; k0 < K; k0 += 32, kb ^= 1) {
        __syncthreads();
        const int kn = (k0 + 32 < K) ? (k0 + 32) : 0;
        GLD16(ag0 + kn, &sA[kb ^ 1][loa0]); GLD16(ag1 + kn, &sA[kb ^ 1][loa1]);
        GLD16(bg0 + kn, &sB[kb ^ 1][lob0]); GLD16(bg1 + kn, &sB[kb ^ 1][lob1]);
        GLD16(bg2 + kn, &sB[kb ^ 1][lob2]); GLD16(bg3 + kn, &sB[kb ^ 1][lob3]);

        bf16x8 a[4], b[8];
#pragma unroll
        for (int i = 0; i < 4; ++i)
            a[i] = *reinterpret_cast<const bf16x8*>(&sA[kb][(wr + i * 16 + m16) * 32 + quad * 8]);
#pragma unroll
        for (int j = 0; j < 8; ++j)
            b[j] = *reinterpret_cast<const bf16x8*>(&sB[kb][(wc + j * 16 + m16) * 32 + quad * 8]);
#pragma unroll
        for (int i = 0; i < 4; ++i)
#pragma unroll
            for (int j = 0; j < 8; ++j)
                acc[i][j] = __builtin_amdgcn_mfma_f32_16x16x32_bf16(a[i], b[j], acc[i][j], 0, 0, 0);
    }

    // epilogue: C/D layout col=lane&15, row=quad*4+r (HW-verified)
    if (mode == 2) {
        float* pcol = psum + (size_t)(wave >> 1) * N_ROWS;  // waves {0,1}->col0, {2,3}->col1
#pragma unroll
        for (int i = 0; i < 4; ++i) {
            const int rbase = row0 + wr + i * 16 + quad * 4;
            float rs[4] = {0.f, 0.f, 0.f, 0.f};
#pragma unroll
            for (int j = 0; j < 8; ++j) {
                const int c = col0 + wc + j * 16 + m16;
#pragma unroll
                for (int r = 0; r < 4; ++r) {
                    const float v = __expf(acc[i][j][r] * INV_T);
                    rs[r] += v;
                    reinterpret_cast<u8*>(C)[(size_t)(rbase + r) * ldc + c] = f2fp8(v);
                }
            }
#pragma unroll
            for (int r = 0; r < 4; ++r) {
                float s = rs[r];
                s += __shfl_down(s, 8, 16);
                s += __shfl_down(s, 4, 16);
                s += __shfl_down(s, 2, 16);
                s += __shfl_down(s, 1, 16);
                if (m16 == 0) pcol[rbase + r] = s;
            }
        }
    } else {
#pragma unroll
        for (int i = 0; i < 4; ++i) {
            const int rbase = row0 + wr + i * 16 + quad * 4;
#pragma unroll
            for (int j = 0; j < 8; ++j) {
                const int c = col0 + wc + j * 16 + m16;
#pragma unroll
                for (int r = 0; r < 4; ++r)
                    reinterpret_cast<u16*>(C)[(size_t)(rbase + r) * ldc + c] = f2bf(acc[i][j][r]);
            }
        }
    }
}

// ---------- batched projection GEMMs ----------
struct ProjArgs {
    const u16* A[3];
    const u16* B[3];
    void*      C[3];
    int        rows[3];
    int        ldc[3];
};

__global__ __launch_bounds__(256, 2)
void proj_gemm(ProjArgs p) {
    const int z = blockIdx.z;
    const int row0 = blockIdx.y * 128;
    if (row0 >= p.rows[z]) return;
    gemm_wide_body(p.A[z], E_DIM, p.B[z], E_DIM, p.C[z], p.ldc[z], E_DIM,
                   row0, blockIdx.x * 256, 1, nullptr);
}

__global__ __launch_bounds__(256, 2)
void gemm_main(const u16* __restrict__ A, int lda,
               const u16* __restrict__ B, int ldb,
               void* __restrict__ C, int ldc, int K, int mode,
               float* __restrict__ psum) {
    float* ps = psum ? psum + (size_t)(blockIdx.x * 2) * N_ROWS : nullptr;
    gemm_wide_body(A, lda, B, ldb, C, ldc, K,
                   blockIdx.y * 128, blockIdx.x * 256, mode, ps);
}

// ---------- PV GEMM, all-fp8 inputs, bf16 out (split-K over grid.z) ----------
// O[i][e] = sum_j P[i][j] * VT[e][j]; P [N x M] fp8, VT [E x M] fp8.
__global__ __launch_bounds__(256, 2)
void pv_fp8(const u8* __restrict__ P, const u8* __restrict__ VT,
            u16* __restrict__ O, int Kslice) {
    __shared__ u8 sA[2][128 * 32];   // 4 KB per buffer
    __shared__ u8 sB[2][256 * 32];   // 8 KB per buffer

    const int z = blockIdx.z;
    const int row0 = blockIdx.y * 128, col0 = blockIdx.x * 256;
    const int tid = threadIdx.x;
    const int wave = tid >> 6, lane = tid & 63;
    const int quad = lane >> 4, m16 = lane & 15;
    const int wr = (wave & 1) * 64, wc = (wave >> 1) * 128;
    const int trow = tid >> 1, toff = (tid & 1) * 16;

    const u8* ag  = P  + (size_t)(row0 + trow) * M_ROWS + z * Kslice + toff;
    const u8* bg0 = VT + (size_t)(col0 + trow) * M_ROWS + z * Kslice + toff;
    const u8* bg1 = bg0 + (size_t)128 * M_ROWS;

    f32x4 acc[4][8];
#pragma unroll
    for (int i = 0; i < 4; ++i)
#pragma unroll
        for (int j = 0; j < 8; ++j) acc[i][j] = (f32x4){0.f, 0.f, 0.f, 0.f};

    GLD16(ag,  &sA[0][tid * 16]);
    GLD16(bg0, &sB[0][tid * 16]);
    GLD16(bg1, &sB[0][4096 + tid * 16]);

    int kb = 0;
    for (int k0 = 0; k0 < Kslice; k0 += 32, kb ^= 1) {
        __syncthreads();
        const int kn = (k0 + 32 < Kslice) ? (k0 + 32) : 0;
        GLD16(ag + kn,  &sA[kb ^ 1][tid * 16]);
        GLD16(bg0 + kn, &sB[kb ^ 1][tid * 16]);
        GLD16(bg1 + kn, &sB[kb ^ 1][4096 + tid * 16]);

        long a[4], b[8];
#pragma unroll
        for (int i = 0; i < 4; ++i)
            a[i] = *reinterpret_cast<const long*>(&sA[kb][(wr + i * 16 + m16) * 32 + quad * 8]);
#pragma unroll
        for (int j = 0; j < 8; ++j)
            b[j] = *reinterpret_cast<const long*>(&sB[kb][(wc + j * 16 + m16) * 32 + quad * 8]);
#pragma unroll
        for (int i = 0; i < 4; ++i)
#pragma unroll
            for (int j = 0; j < 8; ++j)
                acc[i][j] = __builtin_amdgcn_mfma_f32_16x16x32_fp8_fp8(a[i], b[j], acc[i][j], 0, 0, 0);
    }

    u16* Oz = O + (size_t)z * N_ROWS * E_DIM;
#pragma unroll
    for (int i = 0; i < 4; ++i) {
        const int rbase = row0 + wr + i * 16 + quad * 4;
#pragma unroll
        for (int j = 0; j < 8; ++j) {
            const int c = col0 + wc + j * 16 + m16;
#pragma unroll
            for (int r = 0; r < 4; ++r)
                Oz[(size_t)(rbase + r) * E_DIM + c] = f2bf(acc[i][j][r]);
        }
    }
}

// ---------- self attention score: dot(T[n], vcode[n]) ----------
__global__ __launch_bounds__(256)
void self_dot(const u16* __restrict__ q, const u16* __restrict__ k,
              float* __restrict__ selfS) {
    const int wave = threadIdx.x >> 6, lane = threadIdx.x & 63;
    const int row = blockIdx.x * 4 + wave;
    const uint4 qa = *reinterpret_cast<const uint4*>(q + (size_t)row * E_DIM + lane * 8);
    const uint4 ka = *reinterpret_cast<const uint4*>(k + (size_t)row * E_DIM + lane * 8);
    unsigned qu[4] = {qa.x, qa.y, qa.z, qa.w};
    unsigned ku[4] = {ka.x, ka.y, ka.z, ka.w};
    float s = 0.f;
#pragma unroll
    for (int i = 0; i < 4; ++i) {
        s += bf2f((u16)(qu[i] & 0xFFFF)) * bf2f((u16)(ku[i] & 0xFFFF));
        s += bf2f((u16)(qu[i] >> 16))    * bf2f((u16)(ku[i] >> 16));
    }
#pragma unroll
    for (int off = 32; off; off >>= 1) s += __shfl_down(s, off);
    if (lane == 0) selfS[row] = s;
}

// ---------- combine 32 partial row sums -> inv_l, p0 ----------
__global__ __launch_bounds__(256)
void sum_combine(const float* __restrict__ psum, const float* __restrict__ selfS,
                 float* __restrict__ p0_out, float* __restrict__ invl_out) {
    const int n = blockIdx.x * 256 + threadIdx.x;
    float l = 0.f;
#pragma unroll
    for (int j = 0; j < 32; ++j) l += psum[(size_t)j * N_ROWS + n];
    const float p0 = expf(selfS[n] * INV_T);
    l += p0;
    p0_out[n] = p0;
    invl_out[n] = 1.f / l;
}

// ---------- epilogue: LN(inv_l*(p0*v_value + sum_z O_z) + v_code) ----------
__global__ __launch_bounds__(256)
void final_ln(const u16* __restrict__ O, const u16* __restrict__ vval,
              const float* __restrict__ p0v, const float* __restrict__ invl,
              const float* __restrict__ vcode,
              const float* __restrict__ gamma, const float* __restrict__ beta,
              float* __restrict__ out) {
    __shared__ float lds[8];
    const int n = blockIdx.x, t = threadIdx.x;
    const int lane = t & 63, wave = t >> 6;
    const size_t base = (size_t)n * E_DIM;
    const size_t NE = (size_t)N_ROWS * E_DIM;
    const float a = p0v[n], il = invl[n];

    float o0 = 0.f, o1 = 0.f;
#pragma unroll
    for (int z = 0; z < KSPLIT; ++z) {
        o0 += bf2f(O[z * NE + base + t]);
        o1 += bf2f(O[z * NE + base + t + 256]);
    }
    float x0 = fmaf(a, bf2f(vval[base + t]),       o0) * il + vcode[base + t];
    float x1 = fmaf(a, bf2f(vval[base + t + 256]), o1) * il + vcode[base + t + 256];

    float s = x0 + x1;
#pragma unroll
    for (int off = 32; off; off >>= 1) s += __shfl_down(s, off);
    if (lane == 0) lds[wave] = s;
    __syncthreads();
    const float mu = (lds[0] + lds[1] + lds[2] + lds[3]) * (1.0f / E_DIM);
    __syncthreads();

    const float d0 = x0 - mu, d1 = x1 - mu;
    float vs = d0 * d0 + d1 * d1;
#pragma unroll
    for (int off = 32; off; off >>= 1) vs += __shfl_down(vs, off);
    if (lane == 0) lds[wave] = vs;
    __syncthreads();
    const float var = (lds[0] + lds[1] + lds[2] + lds[3]) * (1.0f / E_DIM);
    const float rs = rsqrtf(var + 1e-6f);

    out[base + t]       = d0 * rs * gamma[t]       + beta[t];
    out[base + t + 256] = d1 * rs * gamma[t + 256] + beta[t + 256];
}

// ---------- workspace layout (bytes; total ~102 MiB) ----------
#define OFF_VCODEBF 0ull
#define OFF_OBSBF   8388608ull
#define OFF_WQ      12582912ull
#define OFF_WK      13107200ull
#define OFF_WV      13631488ull
#define OFF_WQT     14155776ull
#define OFF_WKT     14680064ull
#define OFF_WQKT    15204352ull
#define OFF_TBF     15728640ull
#define OFF_OBSV    24117248ull
#define OFF_OBSVT8  28311552ull      // fp8 [512 x 4096] = 2 MiB
#define OFF_VVAL    30408704ull      // bf16, 8 MiB
#define OFF_S8      38797312ull      // fp8 P~ [8192 x 4096] = 32 MiB
#define OFF_O       72351744ull      // KSPLIT bf16 slices (32 MiB)
#define OFF_P0      105906176ull
#define OFF_SELF    105938944ull
#define OFF_INVL    105971712ull
#define OFF_PSUM    106004480ull     // 32 x 8192 fp32 = 1 MiB

extern "C" void kernel_launch(void* const* d_in, const int* in_sizes, int n_in,
                              void* d_out, int out_size, void* d_ws, size_t ws_size,
                              hipStream_t stream) {
    const float* v_code   = (const float*)d_in[0];
    const float* obs_code = (const float*)d_in[1];
    const float* Wq       = (const float*)d_in[2];
    const float* Wk       = (const float*)d_in[3];
    const float* Wv       = (const float*)d_in[4];
    const float* gamma    = (const float*)d_in[5];
    const float* beta     = (const float*)d_in[6];
    float* out = (float*)d_out;
    char* ws = (char*)d_ws;

    u16* vcode_bf = (u16*)(ws + OFF_VCODEBF);
    u16* obs_bf   = (u16*)(ws + OFF_OBSBF);
    u16* wq_bf    = (u16*)(ws + OFF_WQ);
    u16* wk_bf    = (u16*)(ws + OFF_WK);
    u16* wv_bf    = (u16*)(ws + OFF_WV);
    u16* wqT      = (u16*)(ws + OFF_WQT);
    u16* wkT      = (u16*)(ws + OFF_WKT);
    u16* wqkT     = (u16*)(ws + OFF_WQKT);
    u16* t_bf     = (u16*)(ws + OFF_TBF);
    u16* obsv_bf  = (u16*)(ws + OFF_OBSV);
    u8*  obsvT8   = (u8*)(ws + OFF_OBSVT8);
    u16* vval     = (u16*)(ws + OFF_VVAL);
    u8*  S8       = (u8*)(ws + OFF_S8);
    u16* O        = (u16*)(ws + OFF_O);
    float* p0v    = (float*)(ws + OFF_P0);
    float* selfS  = (float*)(ws + OFF_SELF);
    float* invl   = (float*)(ws + OFF_INVL);
    float* psum   = (float*)(ws + OFF_PSUM);

    // 1. casts (big inputs; 3 weights batched into one launch)
    cast_bf<<<N_ROWS * E_DIM / 4 / 256, 256, 0, stream>>>(v_code, vcode_bf, N_ROWS * E_DIM / 4);
    cast_bf<<<M_ROWS * E_DIM / 4 / 256, 256, 0, stream>>>(obs_code, obs_bf, M_ROWS * E_DIM / 4);
    WCastArgs wc;
    wc.src[0] = Wq; wc.dst[0] = wq_bf;
    wc.src[1] = Wk; wc.dst[1] = wk_bf;
    wc.src[2] = Wv; wc.dst[2] = wv_bf;
    cast_w3<<<dim3(E_DIM * E_DIM / 4 / 256, 1, 3), 256, 0, stream>>>(wc);

    // 2. transpose Wq, Wk (one launch)
    transpose_w2<<<dim3(8, 8, 2), 256, 0, stream>>>(wq_bf, wqT, wk_bf, wkT);

    // 3. WqkT = (Wq^T Wk)^T
    gemm_main<<<dim3(E_DIM / 256, E_DIM / 128, 1), 256, 0, stream>>>(
        wkT, E_DIM, wqT, E_DIM, wqkT, E_DIM, E_DIM, 1, nullptr);

    // 4. projections: vval (bf16), obsv (bf16), T = vcode@Wqk (bf16)
    ProjArgs p;
    p.A[0] = vcode_bf; p.B[0] = wv_bf; p.C[0] = vval;    p.rows[0] = N_ROWS; p.ldc[0] = E_DIM;
    p.A[1] = obs_bf;   p.B[1] = wv_bf; p.C[1] = obsv_bf; p.rows[1] = M_ROWS; p.ldc[1] = E_DIM;
    p.A[2] = vcode_bf; p.B[2] = wqkT;  p.C[2] = t_bf;    p.rows[2] = N_ROWS; p.ldc[2] = E_DIM;
    proj_gemm<<<dim3(E_DIM / 256, N_ROWS / 128, 3), 256, 0, stream>>>(p);

    // 5. transpose+quantize obsv -> obsvT8 fp8 [512 x 4096]
    transpose_to_fp8<<<dim3(E_DIM / 64, M_ROWS / 64), 256, 0, stream>>>(
        obsv_bf, obsvT8, M_ROWS, E_DIM);

    // 6. self score
    self_dot<<<N_ROWS / 4, 256, 0, stream>>>(t_bf, vcode_bf, selfS);

    // 7. scores + fused exp: P~ = exp((T @ obs^T)/T) fp8, partial row sums -> psum[32][8192]
    gemm_main<<<dim3(M_ROWS / 256, N_ROWS / 128, 1), 256, 0, stream>>>(
        t_bf, E_DIM, obs_bf, E_DIM, S8, M_ROWS, E_DIM, 2, psum);

    // 8. combine partials + self term -> p0, 1/l
    sum_combine<<<N_ROWS / 256, 256, 0, stream>>>(psum, selfS, p0v, invl);

    // 9. O_z = P~[:, z-slice] @ V_obs[z-slice, :]  (all-fp8 GEMM, split-K=4, bf16 slices)
    pv_fp8<<<dim3(E_DIM / 256, N_ROWS / 128, KSPLIT), 256, 0, stream>>>(
        S8, obsvT8, O, M_ROWS / KSPLIT);

    // 10. residual + LayerNorm
    final_ln<<<N_ROWS, 256, 0, stream>>>(O, vval, p0v, invl, v_code, gamma, beta, out);
}